// Round 11
// baseline (327.467 us; speedup 1.0000x reference)
//
#include <hip/hip_runtime.h>

#define N_NODES 100000
#define N_EDGES 1600000
#define NFEAT 128
#define NHID 64
#define NCLASS 16

#define BSHIFT 8                                   // 256 nodes per bucket
#define BUCK_NODES 256
#define NBUCK ((N_NODES + BUCK_NODES - 1) >> BSHIFT)   // 391
#define EDGE_TILE 2048
#define NB_SCAT ((N_EDGES + EDGE_TILE - 1) / EDGE_TILE) // 782
#define N_TILES (N_NODES / 64 + 1)                      // 1563 tiles of 64 nodes
#define NB_GEMM1 782                                    // grid-stride: 2 tiles/block
#define N_PAD 100032                                    // h rows padded to 64-multiple

typedef __attribute__((ext_vector_type(8))) short short8;
typedef __attribute__((ext_vector_type(4))) float float4v;

__device__ __forceinline__ float bf2f(unsigned short u) {
    return __uint_as_float(((unsigned int)u) << 16);
}
__device__ __forceinline__ float bflo(unsigned int u) {
    return __uint_as_float(u << 16);
}
__device__ __forceinline__ float bfhi(unsigned int u) {
    return __uint_as_float(u & 0xFFFF0000u);
}
__device__ __forceinline__ unsigned short f2bf(float f) {
    unsigned int b = __float_as_uint(f);
    b += 0x7FFFu + ((b >> 16) & 1u);   // RNE
    return (unsigned short)(b >> 16);
}
// packed edge: src in bits [0,17), weight fixed-point 15b in [17,32)
__device__ __forceinline__ float wdec(unsigned int u) {
    return (float)(u >> 17) * (1.0f / 32767.0f);
}

// ---------------------------------------------------------------------------
// Fused: MFMA gemm1 (blocks 0..781) + bucket histogram (blocks 782..1563)
// ---------------------------------------------------------------------------
__global__ __launch_bounds__(256) void k_gemm1_hist(const float* __restrict__ x,
                                                    const float* __restrict__ W1,
                                                    unsigned short* __restrict__ s1,
                                                    const int* __restrict__ dst,
                                                    int* __restrict__ bucket_cnt) {
    __shared__ unsigned short w1t[64][136];
    __shared__ int hist[NBUCK];
    if (blockIdx.x >= NB_GEMM1) {
        const int bid = blockIdx.x - NB_GEMM1;
        for (int i = threadIdx.x; i < NBUCK; i += 256) hist[i] = 0;
        __syncthreads();
        const int base = bid * EDGE_TILE;
        for (int i = threadIdx.x; i < EDGE_TILE; i += 256) {
            int e = base + i;
            if (e < N_EDGES) atomicAdd(&hist[dst[e] >> BSHIFT], 1);
        }
        __syncthreads();
        for (int i = threadIdx.x; i < NBUCK; i += 256)
            if (hist[i]) atomicAdd(&bucket_cnt[i], hist[i]);
        return;
    }
    for (int i = threadIdx.x; i < NFEAT * NHID; i += 256) {
        int n = i & 63, k = i >> 6;
        w1t[n][k] = f2bf(W1[k * NHID + n]);
    }
    __syncthreads();

    const int lane = threadIdx.x & 63;
    const int wv   = threadIdx.x >> 6;
    const int m    = lane & 15;
    const int quad = lane >> 4;

    short8 bfrag[4][4];
#pragma unroll
    for (int kt = 0; kt < 4; ++kt)
#pragma unroll
        for (int nt = 0; nt < 4; ++nt)
            bfrag[kt][nt] = *(const short8*)&w1t[nt * 16 + m][kt * 32 + quad * 8];

    for (int tile = blockIdx.x; tile < N_TILES; tile += NB_GEMM1) {
        const int node0 = tile * 64 + wv * 16;
        if (node0 >= N_NODES) continue;
        const float4* xr = (const float4*)(x + (size_t)node0 * NFEAT);
        float4v acc[4] = {{0.f,0.f,0.f,0.f},{0.f,0.f,0.f,0.f},
                          {0.f,0.f,0.f,0.f},{0.f,0.f,0.f,0.f}};
#pragma unroll
        for (int kt = 0; kt < 4; ++kt) {
            float4 f0 = xr[m * 32 + kt * 8 + quad * 2];
            float4 f1 = xr[m * 32 + kt * 8 + quad * 2 + 1];
            short8 a;
            a[0] = (short)f2bf(f0.x); a[1] = (short)f2bf(f0.y);
            a[2] = (short)f2bf(f0.z); a[3] = (short)f2bf(f0.w);
            a[4] = (short)f2bf(f1.x); a[5] = (short)f2bf(f1.y);
            a[6] = (short)f2bf(f1.z); a[7] = (short)f2bf(f1.w);
#pragma unroll
            for (int nt = 0; nt < 4; ++nt)
                acc[nt] = __builtin_amdgcn_mfma_f32_16x16x32_bf16(
                    a, bfrag[kt][nt], acc[nt], 0, 0, 0);
        }
#pragma unroll
        for (int nt = 0; nt < 4; ++nt)
#pragma unroll
            for (int i = 0; i < 4; ++i)
                s1[(size_t)(node0 + quad * 4 + i) * NHID + nt * 16 + m] =
                    f2bf(acc[nt][i]);
    }
}

// ---------------------------------------------------------------------------
// Exclusive scan of 391 bucket counts (single block, 2 per thread)
// ---------------------------------------------------------------------------
__global__ __launch_bounds__(256) void k_bscan(const int* __restrict__ bucket_cnt,
                                               int* __restrict__ bucket_ptr,
                                               int* __restrict__ fill,
                                               int* __restrict__ row_ptr) {
    __shared__ int ts[256];
    const int i0 = threadIdx.x * 2, i1 = i0 + 1;
    int v0 = (i0 < NBUCK) ? bucket_cnt[i0] : 0;
    int v1 = (i1 < NBUCK) ? bucket_cnt[i1] : 0;
    ts[threadIdx.x] = v0 + v1;
    __syncthreads();
    for (int off = 1; off < 256; off <<= 1) {
        int t = (threadIdx.x >= off) ? ts[threadIdx.x - off] : 0;
        __syncthreads();
        ts[threadIdx.x] += t;
        __syncthreads();
    }
    int excl = threadIdx.x ? ts[threadIdx.x - 1] : 0;
    if (i0 < NBUCK) { bucket_ptr[i0] = excl;      fill[i0] = excl; }
    if (i1 < NBUCK) { bucket_ptr[i1] = excl + v0; fill[i1] = excl + v0; }
    if (threadIdx.x == 0) { bucket_ptr[NBUCK] = N_EDGES; row_ptr[N_NODES] = N_EDGES; }
}

// ---------------------------------------------------------------------------
// Bucket-scatter.  edgeA record: (src 17b | local_dst 8b, fp32 weight)
// ---------------------------------------------------------------------------
__global__ __launch_bounds__(256) void k_bscatter(const int* __restrict__ dst,
                                                  const int* __restrict__ src,
                                                  const float* __restrict__ ew,
                                                  int* __restrict__ fill,
                                                  int2* __restrict__ edgeA) {
    __shared__ int hist[NBUCK], bbase[NBUCK], bfill[NBUCK];
    for (int i = threadIdx.x; i < NBUCK; i += 256) { hist[i] = 0; bfill[i] = 0; }
    __syncthreads();
    const int base = blockIdx.x * EDGE_TILE;
    for (int i = threadIdx.x; i < EDGE_TILE; i += 256) {
        int e = base + i;
        if (e < N_EDGES) atomicAdd(&hist[dst[e] >> BSHIFT], 1);
    }
    __syncthreads();
    for (int i = threadIdx.x; i < NBUCK; i += 256)
        bbase[i] = hist[i] ? atomicAdd(&fill[i], hist[i]) : 0;
    __syncthreads();
    for (int i = threadIdx.x; i < EDGE_TILE; i += 256) {
        int e = base + i;
        if (e >= N_EDGES) break;
        int d = dst[e];
        int b = d >> BSHIFT;
        int r = atomicAdd(&bfill[b], 1);
        edgeA[bbase[b] + r] = make_int2(src[e] | ((d & (BUCK_NODES - 1)) << 17),
                                        __float_as_int(ew[e]));
    }
}

// ---------------------------------------------------------------------------
// In-bucket exact sort by dst; emits row_ptr + packed 4 B records
// ---------------------------------------------------------------------------
__global__ __launch_bounds__(256) void k_bsort(const int* __restrict__ bucket_ptr,
                                               const int2* __restrict__ edgeA,
                                               unsigned int* __restrict__ edgeB,
                                               int* __restrict__ row_ptr) {
    __shared__ int hist[BUCK_NODES], rstart[BUCK_NODES], lfill[BUCK_NODES];
    __shared__ int ts[256];
    const int b = blockIdx.x;
    const int beg = bucket_ptr[b], end = bucket_ptr[b + 1];
    hist[threadIdx.x] = 0; lfill[threadIdx.x] = 0;
    __syncthreads();
    for (int p = beg + threadIdx.x; p < end; p += 256)
        atomicAdd(&hist[edgeA[p].x >> 17], 1);
    __syncthreads();
    int a0 = hist[threadIdx.x];
    ts[threadIdx.x] = a0;
    __syncthreads();
    for (int off = 1; off < 256; off <<= 1) {
        int t = (threadIdx.x >= off) ? ts[threadIdx.x - off] : 0;
        __syncthreads();
        ts[threadIdx.x] += t;
        __syncthreads();
    }
    int excl = threadIdx.x ? ts[threadIdx.x - 1] : 0;
    rstart[threadIdx.x] = excl;
    __syncthreads();
    const int node0 = b << BSHIFT;
    {
        int n = node0 + threadIdx.x;
        if (n < N_NODES) row_ptr[n] = beg + excl;
    }
    for (int p = beg + threadIdx.x; p < end; p += 256) {
        int2 e = edgeA[p];
        int ld = e.x >> 17;
        int r = atomicAdd(&lfill[ld], 1);
        unsigned int w15 = (unsigned int)(__int_as_float(e.y) * 32767.0f + 0.5f);
        edgeB[beg + rstart[ld] + r] = (unsigned int)(e.x & 0x1FFFF) | (w15 << 17);
    }
}

// ---------------------------------------------------------------------------
// agg1, feature-sliced & XCD-pinned: h[n][pass*16..+16) = relu(gather+b1)
// Block = (node quad, pass): G = blockIdx>>3, k8 = blockIdx&7,
// pass = k8>>1 (XCD-pair pinned via round-robin blockIdx->XCD),
// quad = G*2 + (k8&1).  Per-pass s1 slice = 3.2 MB -> fits 4 MB L2.
// Wave per node: 16 edge slots x 4 lanes x uint2 = 512 B/instr, 32 edges/iter.
// ---------------------------------------------------------------------------
__global__ __launch_bounds__(256) void k_agg1(const int* __restrict__ row_ptr,
                                              const unsigned int* __restrict__ edge2,
                                              const unsigned short* __restrict__ s1,
                                              const float* __restrict__ b1,
                                              unsigned short* __restrict__ h) {
    const int G    = blockIdx.x >> 3;
    const int k8   = blockIdx.x & 7;
    const int pass = k8 >> 1;
    const int n    = (G * 2 + (k8 & 1)) * 4 + (threadIdx.x >> 6);
    const int sub  = (threadIdx.x >> 2) & 15;
    const int r    = threadIdx.x & 3;
    const uint2* __restrict__ s1u2 = (const uint2*)s1;   // row = 16 uint2
    const int fo = pass * 4 + r;                          // uint2 index in row

    const int beg = row_ptr[n], end = row_ptr[n + 1];
    float a0 = 0.f, a1 = 0.f, a2 = 0.f, a3 = 0.f;

    int p = beg;
    for (; p + 32 <= end; p += 32) {
        unsigned int e0 = edge2[p + sub];
        unsigned int e1 = edge2[p + sub + 16];
        uint2 u0 = s1u2[(size_t)(e0 & 0x1FFFF) * 16 + fo];
        uint2 u1 = s1u2[(size_t)(e1 & 0x1FFFF) * 16 + fo];
        float w0 = wdec(e0), w1 = wdec(e1);
        a0 += w0 * bflo(u0.x); a1 += w0 * bfhi(u0.x);
        a2 += w0 * bflo(u0.y); a3 += w0 * bfhi(u0.y);
        a0 += w1 * bflo(u1.x); a1 += w1 * bfhi(u1.x);
        a2 += w1 * bflo(u1.y); a3 += w1 * bfhi(u1.y);
    }
    if (p < end) {   // masked epilogue, 1..31 edges
        int i0 = p + sub, i1 = p + sub + 16;
        unsigned int e0 = edge2[min(i0, end - 1)];
        unsigned int e1 = edge2[min(i1, end - 1)];
        uint2 u0 = s1u2[(size_t)(e0 & 0x1FFFF) * 16 + fo];
        uint2 u1 = s1u2[(size_t)(e1 & 0x1FFFF) * 16 + fo];
        float w0 = (i0 < end) ? wdec(e0) : 0.f;
        float w1 = (i1 < end) ? wdec(e1) : 0.f;
        a0 += w0 * bflo(u0.x); a1 += w0 * bfhi(u0.x);
        a2 += w0 * bflo(u0.y); a3 += w0 * bfhi(u0.y);
        a0 += w1 * bflo(u1.x); a1 += w1 * bfhi(u1.x);
        a2 += w1 * bflo(u1.y); a3 += w1 * bfhi(u1.y);
    }
    // combine across the 16 edge slots (lane bits 2..5)
#pragma unroll
    for (int off = 4; off <= 32; off <<= 1) {
        a0 += __shfl_xor(a0, off); a1 += __shfl_xor(a1, off);
        a2 += __shfl_xor(a2, off); a3 += __shfl_xor(a3, off);
    }
    if (sub == 0) {
        const int f = pass * 16 + r * 4;
        float4 bb = *(const float4*)&b1[f];
        unsigned int lo = (unsigned int)f2bf(fmaxf(a0 + bb.x, 0.f)) |
                          ((unsigned int)f2bf(fmaxf(a1 + bb.y, 0.f)) << 16);
        unsigned int hi = (unsigned int)f2bf(fmaxf(a2 + bb.z, 0.f)) |
                          ((unsigned int)f2bf(fmaxf(a3 + bb.w, 0.f)) << 16);
        *(uint2*)&h[(size_t)n * NHID + f] = make_uint2(lo, hi);
    }
}

// ---------------------------------------------------------------------------
// s2 = bf16(h @ W2)  — MFMA, 64 nodes/block (4 waves x 16), 2 MFMAs/wave
// ---------------------------------------------------------------------------
__global__ __launch_bounds__(256) void k_gemm2(const unsigned short* __restrict__ h,
                                               const float* __restrict__ W2,
                                               unsigned short* __restrict__ s2) {
    __shared__ unsigned short w2t[16][72];   // [c][k], 144 B rows (16B aligned)
    for (int i = threadIdx.x; i < NHID * NCLASS; i += 256) {
        int kk = i >> 4, c = i & 15;
        w2t[c][kk] = f2bf(W2[i]);
    }
    __syncthreads();
    const int lane = threadIdx.x & 63;
    const int wv   = threadIdx.x >> 6;
    const int m    = lane & 15;
    const int quad = lane >> 4;
    short8 bf0 = *(const short8*)&w2t[m][quad * 8];
    short8 bf1 = *(const short8*)&w2t[m][32 + quad * 8];

    const int node0 = blockIdx.x * 64 + wv * 16;
    const short8* hrow = (const short8*)&h[(size_t)(node0 + m) * NHID];
    short8 af0 = hrow[quad];
    short8 af1 = hrow[4 + quad];
    float4v acc = {0.f, 0.f, 0.f, 0.f};
    acc = __builtin_amdgcn_mfma_f32_16x16x32_bf16(af0, bf0, acc, 0, 0, 0);
    acc = __builtin_amdgcn_mfma_f32_16x16x32_bf16(af1, bf1, acc, 0, 0, 0);
#pragma unroll
    for (int i = 0; i < 4; ++i) {
        int n = node0 + quad * 4 + i;
        if (n < N_NODES) s2[(size_t)n * NCLASS + m] = f2bf(acc[i]);
    }
}

// ---------------------------------------------------------------------------
// out = log_softmax(gather(s2) + b2)   (unchanged from R10)
// ---------------------------------------------------------------------------
__global__ __launch_bounds__(256) void k_agg2lsm(const int* __restrict__ row_ptr,
                                                 const unsigned int* __restrict__ edge2,
                                                 const unsigned short* __restrict__ s2,
                                                 const float* __restrict__ b2,
                                                 float* __restrict__ out) {
    const unsigned int* __restrict__ s2u = (const unsigned int*)s2;  // row = 8 uints
    const int n = blockIdx.x * 32 + (threadIdx.x >> 3);
    const int r = threadIdx.x & 7;
    const int beg = row_ptr[n], end = row_ptr[n + 1];
    float a0 = 0.f, a1 = 0.f;
    int p = beg;
    for (; p + 8 <= end; p += 8) {
        unsigned int ee[8];
#pragma unroll
        for (int k = 0; k < 8; ++k) ee[k] = edge2[p + k];
#pragma unroll
        for (int k = 0; k < 8; ++k) {
            unsigned int u = s2u[(size_t)(ee[k] & 0x1FFFF) * 8 + r];
            float wv = wdec(ee[k]);
            a0 += wv * bflo(u);
            a1 += wv * bfhi(u);
        }
    }
    if (p < end) {
        unsigned int ee[8];
        float wv[8];
#pragma unroll
        for (int k = 0; k < 8; ++k) {
            int idx = p + k;
            ee[k] = edge2[min(idx, end - 1)];
            wv[k] = (idx < end) ? wdec(ee[k]) : 0.f;
        }
#pragma unroll
        for (int k = 0; k < 8; ++k) {
            unsigned int u = s2u[(size_t)(ee[k] & 0x1FFFF) * 8 + r];
            a0 += wv[k] * bflo(u);
            a1 += wv[k] * bfhi(u);
        }
    }
    float v0 = a0 + b2[2 * r];
    float v1 = a1 + b2[2 * r + 1];
    float m = fmaxf(v0, v1);
#pragma unroll
    for (int off = 4; off >= 1; off >>= 1) m = fmaxf(m, __shfl_xor(m, off, 8));
    float s = __expf(v0 - m) + __expf(v1 - m);
#pragma unroll
    for (int off = 4; off >= 1; off >>= 1) s += __shfl_xor(s, off, 8);
    float ls = __logf(s);
    float2 o = make_float2(v0 - m - ls, v1 - m - ls);
    *(float2*)(out + (size_t)n * NCLASS + 2 * r) = o;
}

extern "C" void kernel_launch(void* const* d_in, const int* in_sizes, int n_in,
                              void* d_out, int out_size, void* d_ws, size_t ws_size,
                              hipStream_t stream) {
    const float* x   = (const float*)d_in[0];
    const int*   src = (const int*)d_in[1];
    const int*   dst = (const int*)d_in[2];
    const float* ew  = (const float*)d_in[3];
    const float* W1  = (const float*)d_in[4];
    const float* b1  = (const float*)d_in[5];
    const float* W2  = (const float*)d_in[6];
    const float* b2  = (const float*)d_in[7];
    float* out = (float*)d_out;

    // ws layout (~49 MB): s1 bf16[N*64] | s2 bf16[N*16] | h bf16[N_PAD*64] |
    // edgeA int2[E] | edgeB uint[E] | row_ptr[N+1] | bucket_cnt | bucket_ptr | fill
    unsigned short* s1 = (unsigned short*)d_ws;
    unsigned short* s2 = s1 + (size_t)N_NODES * NHID;
    unsigned short* h  = s2 + (size_t)N_NODES * NCLASS;
    int2* edgeA        = (int2*)(h + (size_t)N_PAD * NHID);
    unsigned int* edgeB = (unsigned int*)(edgeA + N_EDGES);
    int*  row_ptr      = (int*)(edgeB + N_EDGES);
    int*  bucket_cnt   = row_ptr + (N_NODES + 1);
    int*  bucket_ptr   = bucket_cnt + NBUCK;
    int*  fill         = bucket_ptr + (NBUCK + 1);

    hipMemsetAsync(bucket_cnt, 0, sizeof(int) * NBUCK, stream);

    k_gemm1_hist<<<NB_GEMM1 + NB_SCAT, 256, 0, stream>>>(x, W1, s1, dst, bucket_cnt);
    k_bscan     <<<1, 256, 0, stream>>>(bucket_cnt, bucket_ptr, fill, row_ptr);
    k_bscatter  <<<NB_SCAT, 256, 0, stream>>>(dst, src, ew, fill, edgeA);
    k_bsort     <<<NBUCK, 256, 0, stream>>>(bucket_ptr, edgeA, edgeB, row_ptr);

    k_agg1   <<<N_NODES, 256, 0, stream>>>(row_ptr, edgeB, s1, b1, h);
    k_gemm2  <<<(N_NODES + 63) / 64, 256, 0, stream>>>(h, W2, s2);
    k_agg2lsm<<<N_NODES / 32, 256, 0, stream>>>(row_ptr, edgeB, s2, b2, out);
}